// Round 12
// baseline (893.819 us; speedup 1.0000x reference)
//
#include <hip/hip_runtime.h>
#include <hip/hip_bf16.h>
#include <hip/hip_cooperative_groups.h>

namespace cg = cooperative_groups;

// ---------------------------------------------------------------------------
// GCN (3x GCNConv + relu) -> global mean pool -> MLP -> LayerNorm
//
// Algebra (validated r8/r9):
//   A_n = D^-1/2 (A+I) D^-1/2 separable: (A_n h)_i = dinv_i * S(dinv .* h)_i.
//   Aggregate in the SMALLER feature dim (agg commutes with dense W):
//     L1: aggW(x)[37] @ W1   L2: agg(h1')[64] @ (W2,relu,W3)   L3: agg(q)[64]
//
// Pipeline (5 dispatches):
//   coop CSR build (zero|hist|scan|dinv|fill, grid.sync between phases)
//   gcn1  = agg37(dinv[src] wts) -> LDS tile -> @W1 +b1 relu *dinv -> h1'
//   gcn23 = agg64(h1') -> LDS tile -> @W2 +b2 relu @W3 *dinv -> q
//   agg64(q) +b3 relu -> h3
//   pool + MLP + LayerNorm
// ---------------------------------------------------------------------------

// ---------------- cooperative CSR build ----------------

__global__ __launch_bounds__(256)
void csr_build_kernel(const int* __restrict__ rows, const int* __restrict__ cols,
                      const int* __restrict__ batch,
                      int* counts, int* cursor, int* gcnt,
                      int* offs, int* bsum, int* goff, float* dinv,
                      int* esrc, int n, int E, int ng, int NB) {
    cg::grid_group grid = cg::this_grid();
    __shared__ int lds[256];
    const int t   = threadIdx.x;
    const int gsz = gridDim.x * 256;
    const int gid = blockIdx.x * 256 + t;

    // Z: zero the atomically-updated arrays (ws is 0xAA-poisoned)
    for (int i = gid; i < n; i += gsz) { counts[i] = 0; cursor[i] = 0; }
    for (int i = gid; i <= ng; i += gsz) gcnt[i] = 0;
    grid.sync();

    // H: histograms (edge targets + batch)
    for (int e = gid; e < E; e += gsz) atomicAdd(&counts[cols[e]], 1);
    for (int i = gid; i < n; i += gsz) atomicAdd(&gcnt[batch[i]], 1);
    grid.sync();

    // S1: scan 1024-element chunks (4 elems/thread + block scan)
    for (int chunk = blockIdx.x; chunk < NB; chunk += gridDim.x) {
        int i0 = chunk * 1024 + t * 4;
        int x0 = (i0     < n) ? counts[i0]     : 0;
        int x1 = (i0 + 1 < n) ? counts[i0 + 1] : 0;
        int x2 = (i0 + 2 < n) ? counts[i0 + 2] : 0;
        int x3 = (i0 + 3 < n) ? counts[i0 + 3] : 0;
        int s0 = x0, s1 = s0 + x1, s2 = s1 + x2, s3 = s2 + x3;
        lds[t] = s3;
        __syncthreads();
        for (int o = 1; o < 256; o <<= 1) {
            int y = (t >= o) ? lds[t - o] : 0;
            __syncthreads();
            lds[t] += y;
            __syncthreads();
        }
        int excl = lds[t] - s3;
        if (i0     < n) offs[i0]     = excl;
        if (i0 + 1 < n) offs[i0 + 1] = excl + s0;
        if (i0 + 2 < n) offs[i0 + 2] = excl + s1;
        if (i0 + 3 < n) offs[i0 + 3] = excl + s2;
        if (t == 255) bsum[chunk] = excl + s3;
        __syncthreads();
    }
    grid.sync();

    // S2: block 0 scans bsum (NB<=256) then gcnt->goff (ng<=1024)
    if (blockIdx.x == 0) {
        int v = (t < NB) ? bsum[t] : 0;
        lds[t] = v;
        __syncthreads();
        for (int o = 1; o < 256; o <<= 1) {
            int y = (t >= o) ? lds[t - o] : 0;
            __syncthreads();
            lds[t] += y;
            __syncthreads();
        }
        if (t < NB) bsum[t] = lds[t] - v;
        __syncthreads();
        int i0 = t * 4;
        int g0 = (i0     < ng) ? gcnt[i0]     : 0;
        int g1 = (i0 + 1 < ng) ? gcnt[i0 + 1] : 0;
        int g2 = (i0 + 2 < ng) ? gcnt[i0 + 2] : 0;
        int g3 = (i0 + 3 < ng) ? gcnt[i0 + 3] : 0;
        int q0 = g0, q1 = q0 + g1, q2 = q1 + g2, q3 = q2 + g3;
        lds[t] = q3;
        __syncthreads();
        for (int o = 1; o < 256; o <<= 1) {
            int y = (t >= o) ? lds[t - o] : 0;
            __syncthreads();
            lds[t] += y;
            __syncthreads();
        }
        int excl = lds[t] - q3;
        if (i0     < ng) goff[i0]     = excl;
        if (i0 + 1 < ng) goff[i0 + 1] = excl + q0;
        if (i0 + 2 < ng) goff[i0 + 2] = excl + q1;
        if (i0 + 3 < ng) goff[i0 + 3] = excl + q2;
        if (t == 0) goff[ng] = n;
    }
    grid.sync();

    // S3: add chunk offsets; dinv
    for (int i = gid; i < n; i += gsz) {
        offs[i] += bsum[i >> 10];
        dinv[i] = rsqrtf((float)(counts[i] + 1));   // +1 self loop
    }
    if (gid == 0) offs[n] = E;
    grid.sync();

    // F: fill CSR (atomic cursor placement)
    for (int e = gid; e < E; e += gsz) {
        int r = rows[e], c = cols[e];
        int pos = offs[c] + atomicAdd(&cursor[c], 1);
        esrc[pos] = r;
    }
}

// ---------------- gcn1: agg37 (dinv[src] weights) + mm1 fused ----------------
// h1'[r,c] = relu( (dinv_r * S(dinv.*x)_r) @ W1 + b1 )[c] * dinv_r

__global__ __launch_bounds__(256)
void gcn1_kernel(const float* __restrict__ x, const int* __restrict__ offs,
                 const int* __restrict__ esrc, const float* __restrict__ dinv,
                 const float* __restrict__ W1, const float* __restrict__ b1,
                 float* __restrict__ out, int n) {
    constexpr int K = 37, F = 64;
    __shared__ __align__(16) float Ws[K * F];
    __shared__ float xs[32 * K];
    const int t = threadIdx.x;
    const int wid = t >> 6, lane = t & 63;
    const int r0 = blockIdx.x * 32;

    for (int i = t; i < K * F; i += 256) Ws[i] = W1[i];

    // agg phase: wave wid -> rows wid*8 .. wid*8+7 (lane = feature)
    int c = (lane < K) ? lane : (K - 1);
    for (int p = 0; p < 8; ++p) {
        int row = wid * 8 + p;
        int node = r0 + row;
        if (node >= n) break;
        float dv = dinv[node];
        float a0 = dv * x[(size_t)node * K + c];
        float a1 = 0.f, a2 = 0.f, a3 = 0.f, a4 = 0.f, a5 = 0.f, a6 = 0.f, a7 = 0.f;
        int s = offs[node], e = offs[node + 1];
        int k = s;
        for (; k + 7 < e; k += 8) {
            int s0 = esrc[k],     s1 = esrc[k + 1], s2 = esrc[k + 2], s3 = esrc[k + 3];
            int s4 = esrc[k + 4], s5 = esrc[k + 5], s6 = esrc[k + 6], s7 = esrc[k + 7];
            a0 += dinv[s0] * x[(size_t)s0 * K + c];
            a1 += dinv[s1] * x[(size_t)s1 * K + c];
            a2 += dinv[s2] * x[(size_t)s2 * K + c];
            a3 += dinv[s3] * x[(size_t)s3 * K + c];
            a4 += dinv[s4] * x[(size_t)s4 * K + c];
            a5 += dinv[s5] * x[(size_t)s5 * K + c];
            a6 += dinv[s6] * x[(size_t)s6 * K + c];
            a7 += dinv[s7] * x[(size_t)s7 * K + c];
        }
        for (; k < e; ++k) {
            int s0 = esrc[k];
            a0 += dinv[s0] * x[(size_t)s0 * K + c];
        }
        float v = (((a0 + a1) + (a2 + a3)) + ((a4 + a5) + (a6 + a7))) * dv;
        if (lane < K) xs[row * K + c] = v;
    }
    __syncthreads();

    // mm phase: 32 rows x 16 col-groups
    int nrow = n - r0; if (nrow > 32) nrow = 32;
    for (int idx = t; idx < 32 * 16; idx += 256) {
        int r = idx / 16, cg4 = idx % 16;
        if (r >= nrow) break;
        float4 acc = {0.f, 0.f, 0.f, 0.f};
#pragma unroll
        for (int k = 0; k < K; ++k) {
            float xv = xs[r * K + k];
            float4 wv = *reinterpret_cast<const float4*>(&Ws[k * F + cg4 * 4]);
            acc.x += xv * wv.x; acc.y += xv * wv.y;
            acc.z += xv * wv.z; acc.w += xv * wv.w;
        }
        const float4 bv = *reinterpret_cast<const float4*>(&b1[cg4 * 4]);
        float dv = dinv[r0 + r];
        acc.x = fmaxf(acc.x + bv.x, 0.f) * dv;
        acc.y = fmaxf(acc.y + bv.y, 0.f) * dv;
        acc.z = fmaxf(acc.z + bv.z, 0.f) * dv;
        acc.w = fmaxf(acc.w + bv.w, 0.f) * dv;
        *reinterpret_cast<float4*>(&out[(size_t)(r0 + r) * F + cg4 * 4]) = acc;
    }
}

// ---------------- gcn23: agg64 + (W2,relu,W3,*dinv) fused --------------------
// q = (relu( (dinv.*S(h1'))@W2 + b2 ))@W3 .* dinv

__global__ __launch_bounds__(256)
void gcn23_kernel(const float* __restrict__ g, const int* __restrict__ offs,
                  const int* __restrict__ esrc, const float* __restrict__ dinv,
                  const float* __restrict__ W2, const float* __restrict__ b2,
                  const float* __restrict__ W3, float* __restrict__ out, int n) {
    __shared__ __align__(16) float Wbuf[64 * 128];
    __shared__ __align__(16) float Xbuf[32 * 130];
    const int t = threadIdx.x;
    const int wid = t >> 6, lane = t & 63;
    const int r0 = blockIdx.x * 32;

    // load W2 (read after the sync below)
    for (int i = t * 4; i < 8192; i += 1024)
        *reinterpret_cast<float4*>(&Wbuf[i]) = *reinterpret_cast<const float4*>(&W2[i]);

    // agg phase: t1 rows -> Xbuf (stride 68), wave = 8 nodes, lane = feature
    for (int p = 0; p < 8; ++p) {
        int row = wid * 8 + p;
        int node = r0 + row;
        if (node >= n) break;
        float dv = dinv[node];
        float a0 = g[(size_t)node * 64 + lane];
        float a1 = 0.f, a2 = 0.f, a3 = 0.f, a4 = 0.f, a5 = 0.f, a6 = 0.f, a7 = 0.f;
        int s = offs[node], e = offs[node + 1];
        int k = s;
        for (; k + 7 < e; k += 8) {
            int s0 = esrc[k],     s1 = esrc[k + 1], s2 = esrc[k + 2], s3 = esrc[k + 3];
            int s4 = esrc[k + 4], s5 = esrc[k + 5], s6 = esrc[k + 6], s7 = esrc[k + 7];
            a0 += g[(size_t)s0 * 64 + lane];
            a1 += g[(size_t)s1 * 64 + lane];
            a2 += g[(size_t)s2 * 64 + lane];
            a3 += g[(size_t)s3 * 64 + lane];
            a4 += g[(size_t)s4 * 64 + lane];
            a5 += g[(size_t)s5 * 64 + lane];
            a6 += g[(size_t)s6 * 64 + lane];
            a7 += g[(size_t)s7 * 64 + lane];
        }
        for (; k < e; ++k) a0 += g[(size_t)esrc[k] * 64 + lane];
        Xbuf[row * 68 + lane] =
            (((a0 + a1) + (a2 + a3)) + ((a4 + a5) + (a6 + a7))) * dv;
    }
    __syncthreads();

    // phase 1: h2 = relu(t1@W2+b2); thread (tc=t%32, tr=t/32): rows tr+8i
    const int tc = t % 32, tr = t / 32;
    float4 h2[4];
#pragma unroll
    for (int i = 0; i < 4; ++i) h2[i] = float4{0.f, 0.f, 0.f, 0.f};
#pragma unroll 2
    for (int kk = 0; kk < 64; kk += 4) {
        float4 xv[4];
#pragma unroll
        for (int i = 0; i < 4; ++i)
            xv[i] = *reinterpret_cast<const float4*>(&Xbuf[(tr + 8 * i) * 68 + kk]);
        float4 wv[4];
#pragma unroll
        for (int j = 0; j < 4; ++j)
            wv[j] = *reinterpret_cast<const float4*>(&Wbuf[(kk + j) * 128 + tc * 4]);
#pragma unroll
        for (int i = 0; i < 4; ++i) {
            const float* xp = reinterpret_cast<const float*>(&xv[i]);
#pragma unroll
            for (int j = 0; j < 4; ++j) {
                float s = xp[j];
                h2[i].x += s * wv[j].x; h2[i].y += s * wv[j].y;
                h2[i].z += s * wv[j].z; h2[i].w += s * wv[j].w;
            }
        }
    }
    {
        const float4 bv = *reinterpret_cast<const float4*>(&b2[tc * 4]);
#pragma unroll
        for (int i = 0; i < 4; ++i) {
            h2[i].x = fmaxf(h2[i].x + bv.x, 0.f);
            h2[i].y = fmaxf(h2[i].y + bv.y, 0.f);
            h2[i].z = fmaxf(h2[i].z + bv.z, 0.f);
            h2[i].w = fmaxf(h2[i].w + bv.w, 0.f);
        }
    }
    __syncthreads();   // all reads of Wbuf/Xbuf done

    // phase 2: h2 tile -> Xbuf (stride 130); W3 -> Wbuf
#pragma unroll
    for (int i = 0; i < 4; ++i)
        *reinterpret_cast<float4*>(&Xbuf[(tr + 8 * i) * 130 + tc * 4]) = h2[i];
    for (int i = t * 4; i < 8192; i += 1024)
        *reinterpret_cast<float4*>(&Wbuf[i]) = *reinterpret_cast<const float4*>(&W3[i]);
    __syncthreads();

    // phase 3: q = h2@W3 .* dinv; thread (tc3=t%16, tr3=t/16): rows {tr3, tr3+16}
    const int tc3 = t % 16, tr3 = t / 16;
    float4 q0 = {0.f, 0.f, 0.f, 0.f}, q1 = {0.f, 0.f, 0.f, 0.f};
#pragma unroll 2
    for (int k2 = 0; k2 < 128; k2 += 4) {
        float4 x0 = *reinterpret_cast<const float4*>(&Xbuf[tr3 * 130 + k2]);
        float4 x1 = *reinterpret_cast<const float4*>(&Xbuf[(tr3 + 16) * 130 + k2]);
        float4 wv[4];
#pragma unroll
        for (int j = 0; j < 4; ++j)
            wv[j] = *reinterpret_cast<const float4*>(&Wbuf[(k2 + j) * 64 + tc3 * 4]);
        const float* p0 = reinterpret_cast<const float*>(&x0);
        const float* p1 = reinterpret_cast<const float*>(&x1);
#pragma unroll
        for (int j = 0; j < 4; ++j) {
            float s0 = p0[j], s1 = p1[j];
            q0.x += s0 * wv[j].x; q0.y += s0 * wv[j].y;
            q0.z += s0 * wv[j].z; q0.w += s0 * wv[j].w;
            q1.x += s1 * wv[j].x; q1.y += s1 * wv[j].y;
            q1.z += s1 * wv[j].z; q1.w += s1 * wv[j].w;
        }
    }
    int gr0 = r0 + tr3, gr1 = r0 + tr3 + 16;
    if (gr0 < n) {
        float dv = dinv[gr0];
        q0.x *= dv; q0.y *= dv; q0.z *= dv; q0.w *= dv;
        *reinterpret_cast<float4*>(&out[(size_t)gr0 * 64 + tc3 * 4]) = q0;
    }
    if (gr1 < n) {
        float dv = dinv[gr1];
        q1.x *= dv; q1.y *= dv; q1.z *= dv; q1.w *= dv;
        *reinterpret_cast<float4*>(&out[(size_t)gr1 * 64 + tc3 * 4]) = q1;
    }
}

// ---------------- standalone agg (layer 3), validated r9 ---------------------

template <int F, int WSRC>
__global__ __launch_bounds__(256)
void agg_kernel(const float* __restrict__ g, const int* __restrict__ offs,
                const int* __restrict__ esrc, const float* __restrict__ dinv,
                const float* __restrict__ bias, int do_relu,
                float* __restrict__ out, int n) {
    static_assert(F <= 64, "one lane per feature");
    int wid  = threadIdx.x >> 6;
    int lane = threadIdx.x & 63;
    int node = blockIdx.x * 4 + wid;
    if (node >= n) return;
    int c = (lane < F) ? lane : (F - 1);
    float dv = dinv[node];
    float a0 = (WSRC ? dv : 1.0f) * g[(size_t)node * F + c];
    float a1 = 0.f, a2 = 0.f, a3 = 0.f, a4 = 0.f, a5 = 0.f, a6 = 0.f, a7 = 0.f;
    int s = offs[node], e = offs[node + 1];
    int k = s;
    for (; k + 7 < e; k += 8) {
        int s0 = esrc[k],     s1 = esrc[k + 1], s2 = esrc[k + 2], s3 = esrc[k + 3];
        int s4 = esrc[k + 4], s5 = esrc[k + 5], s6 = esrc[k + 6], s7 = esrc[k + 7];
        float w0 = WSRC ? dinv[s0] : 1.f, w1 = WSRC ? dinv[s1] : 1.f;
        float w2 = WSRC ? dinv[s2] : 1.f, w3 = WSRC ? dinv[s3] : 1.f;
        float w4 = WSRC ? dinv[s4] : 1.f, w5 = WSRC ? dinv[s5] : 1.f;
        float w6 = WSRC ? dinv[s6] : 1.f, w7 = WSRC ? dinv[s7] : 1.f;
        a0 += w0 * g[(size_t)s0 * F + c];
        a1 += w1 * g[(size_t)s1 * F + c];
        a2 += w2 * g[(size_t)s2 * F + c];
        a3 += w3 * g[(size_t)s3 * F + c];
        a4 += w4 * g[(size_t)s4 * F + c];
        a5 += w5 * g[(size_t)s5 * F + c];
        a6 += w6 * g[(size_t)s6 * F + c];
        a7 += w7 * g[(size_t)s7 * F + c];
    }
    for (; k < e; ++k) {
        int s0 = esrc[k];
        float w0 = WSRC ? dinv[s0] : 1.f;
        a0 += w0 * g[(size_t)s0 * F + c];
    }
    float v = (((a0 + a1) + (a2 + a3)) + ((a4 + a5) + (a6 + a7))) * dv;
    if (bias)    v += bias[c];
    if (do_relu) v = fmaxf(v, 0.f);
    if (lane < F) out[(size_t)node * F + c] = v;
}

// ---------------- pool + MLP + LayerNorm (one block / graph, 128 thr) --------

__global__ __launch_bounds__(128)
void poolmlp_kernel(const float* __restrict__ h, const int* __restrict__ goff,
                    const float* __restrict__ Wf1, const float* __restrict__ bf1,
                    const float* __restrict__ Wf2, const float* __restrict__ bf2,
                    const float* __restrict__ gamma, const float* __restrict__ beta,
                    float* __restrict__ out) {
    __shared__ float red[128];
    __shared__ float gs[64];
    __shared__ float ts[128];
    int g = blockIdx.x, t = threadIdx.x;
    int f = t & 63, half = t >> 6;
    int s = goff[g], e = goff[g + 1];
    float acc = 0.f;
    for (int i = s + half; i < e; i += 2) acc += h[(size_t)i * 64 + f];
    red[t] = acc;
    __syncthreads();
    if (t < 64) {
        float c = (float)(e - s);
        gs[t] = (red[t] + red[t + 64]) / fmaxf(c, 1.0f);
    }
    __syncthreads();
    float a1 = bf1[t];
    for (int k = 0; k < 64; ++k) a1 += gs[k] * Wf1[k * 128 + t];
    ts[t] = fmaxf(a1, 0.f);
    __syncthreads();
    if (t < 64) {
        float a2 = bf2[t];
        for (int k = 0; k < 128; ++k) a2 += ts[k] * Wf2[k * 64 + t];
        float u = fmaxf(a2, 0.f);
        float mu = u;
        for (int o = 1; o < 64; o <<= 1) mu += __shfl_xor(mu, o);
        mu *= (1.0f / 64.0f);
        float d = u - mu;
        float var = d * d;
        for (int o = 1; o < 64; o <<= 1) var += __shfl_xor(var, o);
        var *= (1.0f / 64.0f);
        out[g * 64 + t] = d * rsqrtf(var + 1e-5f) * gamma[t] + beta[t];
    }
}

// ---------------- launch ----------------

extern "C" void kernel_launch(void* const* d_in, const int* in_sizes, int n_in,
                              void* d_out, int out_size, void* d_ws, size_t ws_size,
                              hipStream_t stream) {
    const float* x     = (const float*)d_in[0];
    const int*   eidx  = (const int*)d_in[1];
    const int*   batch = (const int*)d_in[2];
    const float* W1 = (const float*)d_in[3];  const float* b1 = (const float*)d_in[4];
    const float* W2 = (const float*)d_in[5];  const float* b2 = (const float*)d_in[6];
    const float* W3 = (const float*)d_in[7];  const float* b3 = (const float*)d_in[8];
    const float* Wf1 = (const float*)d_in[9];  const float* bf1 = (const float*)d_in[10];
    const float* Wf2 = (const float*)d_in[11]; const float* bf2 = (const float*)d_in[12];
    const float* gamma = (const float*)d_in[13]; const float* beta = (const float*)d_in[14];
    float* out = (float*)d_out;

    int n  = in_sizes[2];          // 50000
    int E  = in_sizes[1] / 2;      // 600000
    int ng = out_size / 64;        // 1000
    int NB = (n + 1023) / 1024;    // 49

    const int* rows = eidx;        // edge_index[0] (sources)
    const int* cols = eidx + E;    // edge_index[1] (targets)

    // -------- workspace carve --------
    size_t off = 0;
    auto carve = [&](size_t bytes) {
        void* p = (char*)d_ws + off;
        off += (bytes + 511) & ~(size_t)511;
        return p;
    };
    int*   counts = (int*)  carve((size_t)n * 4);
    int*   cursor = (int*)  carve((size_t)n * 4);
    int*   gcnt   = (int*)  carve((size_t)(ng + 1) * 4);
    int*   offs   = (int*)  carve((size_t)(n + 1) * 4);
    int*   bsum   = (int*)  carve((size_t)(NB + 1) * 4);
    int*   goff   = (int*)  carve((size_t)(ng + 1) * 4);
    float* dinv   = (float*)carve((size_t)n * 4);
    int*   esrc   = (int*)  carve((size_t)E * 4);
    float* bufA   = (float*)carve((size_t)n * 64 * 4);   // h1' / h3
    float* bufB   = (float*)carve((size_t)n * 64 * 4);   // q
    (void)ws_size;

    // -------- 1) cooperative CSR build (zero|hist|scan|dinv|fill) --------
    {
        void* args[] = {(void*)&rows, (void*)&cols, (void*)&batch,
                        (void*)&counts, (void*)&cursor, (void*)&gcnt,
                        (void*)&offs, (void*)&bsum, (void*)&goff, (void*)&dinv,
                        (void*)&esrc, (void*)&n, (void*)&E, (void*)&ng, (void*)&NB};
        hipLaunchCooperativeKernel(reinterpret_cast<void*>(csr_build_kernel),
                                   dim3(1024), dim3(256), args, 0, stream);
    }

    // -------- 2..4) layers --------
    int gtile = (n + 31) / 32;
    gcn1_kernel<<<gtile, 256, 0, stream>>>(x, offs, esrc, dinv, W1, b1, bufA, n);
    gcn23_kernel<<<gtile, 256, 0, stream>>>(bufA, offs, esrc, dinv, W2, b2, W3, bufB, n);
    agg_kernel<64, 0><<<(n + 3) / 4, 256, 0, stream>>>(bufB, offs, esrc, dinv, b3, 1,
                                                       bufA, n);

    // -------- 5) pool + MLP + LayerNorm --------
    poolmlp_kernel<<<ng, 128, 0, stream>>>(bufA, goff, Wf1, bf1, Wf2, bf2, gamma, beta, out);
}

// Round 13
// 322.362 us; speedup vs baseline: 2.7727x; 2.7727x over previous
//
#include <hip/hip_runtime.h>
#include <hip/hip_bf16.h>

// ---------------------------------------------------------------------------
// GCN (3x GCNConv + relu) -> global mean pool -> MLP -> LayerNorm
//
// Structure = R9 (discrete CSR chain + standalone high-occupancy aggs), plus:
//   bf16 storage for the two GATHERED intermediates (h1', q) — halves the
//   random-gather traffic that dominates the aggs. Sequentially-read tensors
//   (t0, t1, h3) stay fp32.
//
// Algebra (validated r8/r9):
//   A_n = D^-1/2 (A+I) D^-1/2 separable: (A_n h)_i = dinv_i * S(dinv .* h)_i.
//   Aggregate in the SMALLER feature dim:
//     L1: aggW(x)[37] @ W1   L2: agg(h1')[64] @ (W2,relu,W3)   L3: agg(q)[64]
//
// Pipeline (12 dispatches):
//   memset | hist | scan1 | scan_meta | scan3(dinv) | fill(esrc) |
//   agg37(x,wsrc) | mm1(->bf16 h1') | agg64(bf16) | mm23(->bf16 q) |
//   agg64(bf16,+b3,relu) | pool+mlp+layernorm
// ---------------------------------------------------------------------------

// -------- bf16 helpers (bit-exact b2f; RNE f2b) --------
__device__ __forceinline__ float b2f(unsigned short u) {
    return __uint_as_float(((unsigned int)u) << 16);
}
__device__ __forceinline__ unsigned short f2b(float f) {
    unsigned int i = __float_as_uint(f);
    unsigned int r = i + 0x7FFFu + ((i >> 16) & 1u);
    return (unsigned short)(r >> 16);
}
__device__ __forceinline__ unsigned int pack2(float a, float b) {
    return (unsigned int)f2b(a) | ((unsigned int)f2b(b) << 16);
}
__device__ __forceinline__ float ldg_f(const float* p, size_t i) { return p[i]; }
__device__ __forceinline__ float ldg_f(const unsigned short* p, size_t i) { return b2f(p[i]); }

// ---------------- histograms (edges + batch fused) ----------------

__global__ __launch_bounds__(256)
void hist_kernel(const int* __restrict__ cols, int* __restrict__ counts, int E,
                 const int* __restrict__ batch, int* __restrict__ gcnt, int n) {
    int idx = blockIdx.x * 256 + threadIdx.x;
    if (idx < E) {
        atomicAdd(&counts[cols[idx]], 1);
    } else {
        int i = idx - E;
        if (i < n) atomicAdd(&gcnt[batch[i]], 1);
    }
}

// ---------------- scans ----------------

__global__ __launch_bounds__(1024)
void scan1_kernel(const int* __restrict__ counts, int* __restrict__ offs,
                  int* __restrict__ bsum, int n) {
    __shared__ int tmp[1024];
    int i = blockIdx.x * 1024 + threadIdx.x;
    int v = (i < n) ? counts[i] : 0;
    tmp[threadIdx.x] = v;
    __syncthreads();
    for (int o = 1; o < 1024; o <<= 1) {
        int x = (threadIdx.x >= o) ? tmp[threadIdx.x - o] : 0;
        __syncthreads();
        tmp[threadIdx.x] += x;
        __syncthreads();
    }
    if (i < n) offs[i] = tmp[threadIdx.x] - v;   // exclusive (within block)
    if (threadIdx.x == 1023) bsum[blockIdx.x] = tmp[1023];
}

// scan bsum (nb) AND gcnt->goff (ng) in one block. nb, ng <= 1024.
__global__ __launch_bounds__(1024)
void scan_meta_kernel(int* __restrict__ bsum, int nb,
                      const int* __restrict__ gcnt, int* __restrict__ goff,
                      int ng, int n_nodes) {
    __shared__ int ta[1024];
    __shared__ int tb[1024];
    int t = threadIdx.x;
    int va = (t < nb) ? bsum[t] : 0;
    int vb = (t < ng) ? gcnt[t] : 0;
    ta[t] = va;
    tb[t] = vb;
    __syncthreads();
    for (int o = 1; o < 1024; o <<= 1) {
        int xa = (t >= o) ? ta[t - o] : 0;
        int xb = (t >= o) ? tb[t - o] : 0;
        __syncthreads();
        ta[t] += xa;
        tb[t] += xb;
        __syncthreads();
    }
    if (t < nb) bsum[t] = ta[t] - va;
    if (t < ng) goff[t] = tb[t] - vb;
    if (t == 0) goff[ng] = n_nodes;
}

__global__ __launch_bounds__(256)
void scan3_kernel(int* __restrict__ offs, const int* __restrict__ bsum,
                  const int* __restrict__ counts, float* __restrict__ dinv,
                  int n, int E) {
    int i = blockIdx.x * 256 + threadIdx.x;
    if (i < n) {
        offs[i] += bsum[i >> 10];
        dinv[i] = rsqrtf((float)(counts[i] + 1));  // +1 self loop; always > 0
    }
    if (i == 0) offs[n] = E;
}

__global__ __launch_bounds__(256)
void fill_kernel(const int* __restrict__ rows, const int* __restrict__ cols,
                 const int* __restrict__ offs, int* __restrict__ cursor,
                 int* __restrict__ esrc, int E) {
    int e = blockIdx.x * 256 + threadIdx.x;
    if (e >= E) return;
    int r = rows[e], c = cols[e];
    int pos = offs[c] + atomicAdd(&cursor[c], 1);
    esrc[pos] = r;
}

// ---------------- aggregation (F<=64, wave/node, 8-deep ILP, fp32 or bf16 in) --

template <int F, int WSRC, typename T>
__global__ __launch_bounds__(256)
void agg_kernel(const T* __restrict__ g, const int* __restrict__ offs,
                const int* __restrict__ esrc, const float* __restrict__ dinv,
                const float* __restrict__ bias, int do_relu,
                float* __restrict__ out, int n) {
    static_assert(F <= 64, "one lane per feature");
    int wid  = threadIdx.x >> 6;
    int lane = threadIdx.x & 63;
    int node = blockIdx.x * 4 + wid;
    if (node >= n) return;
    int c = (lane < F) ? lane : (F - 1);          // clamped dup read, write-guarded
    float dv = dinv[node];
    float a0 = (WSRC ? dv : 1.0f) * ldg_f(g, (size_t)node * F + c);
    float a1 = 0.f, a2 = 0.f, a3 = 0.f, a4 = 0.f, a5 = 0.f, a6 = 0.f, a7 = 0.f;
    int s = offs[node], e = offs[node + 1];
    int k = s;
    for (; k + 7 < e; k += 8) {                   // 8 gathers in flight / wave
        int s0 = esrc[k],     s1 = esrc[k + 1], s2 = esrc[k + 2], s3 = esrc[k + 3];
        int s4 = esrc[k + 4], s5 = esrc[k + 5], s6 = esrc[k + 6], s7 = esrc[k + 7];
        float w0 = WSRC ? dinv[s0] : 1.f, w1 = WSRC ? dinv[s1] : 1.f;
        float w2 = WSRC ? dinv[s2] : 1.f, w3 = WSRC ? dinv[s3] : 1.f;
        float w4 = WSRC ? dinv[s4] : 1.f, w5 = WSRC ? dinv[s5] : 1.f;
        float w6 = WSRC ? dinv[s6] : 1.f, w7 = WSRC ? dinv[s7] : 1.f;
        a0 += w0 * ldg_f(g, (size_t)s0 * F + c);
        a1 += w1 * ldg_f(g, (size_t)s1 * F + c);
        a2 += w2 * ldg_f(g, (size_t)s2 * F + c);
        a3 += w3 * ldg_f(g, (size_t)s3 * F + c);
        a4 += w4 * ldg_f(g, (size_t)s4 * F + c);
        a5 += w5 * ldg_f(g, (size_t)s5 * F + c);
        a6 += w6 * ldg_f(g, (size_t)s6 * F + c);
        a7 += w7 * ldg_f(g, (size_t)s7 * F + c);
    }
    for (; k < e; ++k) {
        int s0 = esrc[k];
        float w0 = WSRC ? dinv[s0] : 1.f;
        a0 += w0 * ldg_f(g, (size_t)s0 * F + c);
    }
    float v = (((a0 + a1) + (a2 + a3)) + ((a4 + a5) + (a6 + a7))) * dv;
    if (bias)    v += bias[c];
    if (do_relu) v = fmaxf(v, 0.f);
    if (lane < F) out[(size_t)node * F + c] = v;
}

// ---------------- mm1 (K=37 -> F=64): h1' = relu(t0@W1+b1)*dinv -> BF16 ------

__global__ __launch_bounds__(256)
void mm1_kernel(const float* __restrict__ X, const float* __restrict__ W,
                const float* __restrict__ bias, const float* __restrict__ dscale,
                unsigned short* __restrict__ out, int n) {
    constexpr int K = 37, F = 64;
    __shared__ __align__(16) float Ws[K * F];
    __shared__ float xs[32 * K];
    int r0 = blockIdx.x * 32;
    for (int i = threadIdx.x; i < K * F; i += 256) Ws[i] = W[i];
    int nrow = n - r0; if (nrow > 32) nrow = 32;
    const float* Xb = X + (size_t)r0 * K;
    int tot = nrow * K;
    for (int i = threadIdx.x; i < tot; i += 256) xs[i] = Xb[i];
    __syncthreads();
    for (int idx = threadIdx.x; idx < 32 * 16; idx += 256) {
        int r = idx / 16, cg4 = idx % 16;
        if (r >= nrow) break;
        float4 acc = {0.f, 0.f, 0.f, 0.f};
#pragma unroll
        for (int k = 0; k < K; ++k) {
            float xv = xs[r * K + k];
            float4 wv = *reinterpret_cast<const float4*>(&Ws[k * F + cg4 * 4]);
            acc.x += xv * wv.x; acc.y += xv * wv.y;
            acc.z += xv * wv.z; acc.w += xv * wv.w;
        }
        const float4 bv = *reinterpret_cast<const float4*>(&bias[cg4 * 4]);
        float dv = dscale[r0 + r];
        acc.x = fmaxf(acc.x + bv.x, 0.f) * dv;
        acc.y = fmaxf(acc.y + bv.y, 0.f) * dv;
        acc.z = fmaxf(acc.z + bv.z, 0.f) * dv;
        acc.w = fmaxf(acc.w + bv.w, 0.f) * dv;
        uint2 pk;
        pk.x = pack2(acc.x, acc.y);
        pk.y = pack2(acc.z, acc.w);
        *reinterpret_cast<uint2*>(&out[(size_t)(r0 + r) * F + cg4 * 4]) = pk;
    }
}

// ---------------- fused mm2+mm3: q = (relu(t1@W2+b2))@W3 .* dinv -> BF16 -----
// t1:[n,64] fp32, W2:[64,128], W3:[128,64]. 32-row tile; Wbuf/Xbuf time-shared.

__global__ __launch_bounds__(256)
void mm23_kernel(const float* __restrict__ X, const float* __restrict__ W2,
                 const float* __restrict__ b2, const float* __restrict__ W3,
                 const float* __restrict__ dinv, unsigned short* __restrict__ out,
                 int n) {
    __shared__ __align__(16) float Wbuf[64 * 128];
    __shared__ __align__(16) float Xbuf[32 * 130];
    const int t  = threadIdx.x;
    const int r0 = blockIdx.x * 32;

    // phase 0: load W2 + x-tile
    for (int i = t * 4; i < 8192; i += 1024)
        *reinterpret_cast<float4*>(&Wbuf[i]) = *reinterpret_cast<const float4*>(&W2[i]);
    for (int idx = t; idx < 32 * 16; idx += 256) {
        int row = idx / 16, col = idx % 16;
        int gr = r0 + row; if (gr >= n) gr = n - 1;
        *reinterpret_cast<float4*>(&Xbuf[row * 68 + col * 4]) =
            *reinterpret_cast<const float4*>(&X[(size_t)gr * 64 + col * 4]);
    }
    __syncthreads();

    // phase 1: h2 = relu(x@W2+b2); thread (tc=t%32, tr=t/32): rows tr+8i
    const int tc = t % 32, tr = t / 32;
    float4 h2[4];
#pragma unroll
    for (int i = 0; i < 4; ++i) h2[i] = float4{0.f, 0.f, 0.f, 0.f};
#pragma unroll 2
    for (int kk = 0; kk < 64; kk += 4) {
        float4 xv[4];
#pragma unroll
        for (int i = 0; i < 4; ++i)
            xv[i] = *reinterpret_cast<const float4*>(&Xbuf[(tr + 8 * i) * 68 + kk]);
        float4 wv[4];
#pragma unroll
        for (int j = 0; j < 4; ++j)
            wv[j] = *reinterpret_cast<const float4*>(&Wbuf[(kk + j) * 128 + tc * 4]);
#pragma unroll
        for (int i = 0; i < 4; ++i) {
            const float* xp = reinterpret_cast<const float*>(&xv[i]);
#pragma unroll
            for (int j = 0; j < 4; ++j) {
                float s = xp[j];
                h2[i].x += s * wv[j].x; h2[i].y += s * wv[j].y;
                h2[i].z += s * wv[j].z; h2[i].w += s * wv[j].w;
            }
        }
    }
    {
        const float4 bv = *reinterpret_cast<const float4*>(&b2[tc * 4]);
#pragma unroll
        for (int i = 0; i < 4; ++i) {
            h2[i].x = fmaxf(h2[i].x + bv.x, 0.f);
            h2[i].y = fmaxf(h2[i].y + bv.y, 0.f);
            h2[i].z = fmaxf(h2[i].z + bv.z, 0.f);
            h2[i].w = fmaxf(h2[i].w + bv.w, 0.f);
        }
    }
    __syncthreads();   // all reads of Wbuf/Xbuf done

    // phase 2: write h2 tile (stride 130); load W3 over W2
#pragma unroll
    for (int i = 0; i < 4; ++i)
        *reinterpret_cast<float4*>(&Xbuf[(tr + 8 * i) * 130 + tc * 4]) = h2[i];
    for (int i = t * 4; i < 8192; i += 1024)
        *reinterpret_cast<float4*>(&Wbuf[i]) = *reinterpret_cast<const float4*>(&W3[i]);
    __syncthreads();

    // phase 3: q = h2@W3 .* dinv -> bf16; thread (tc3=t%16, tr3=t/16)
    const int tc3 = t % 16, tr3 = t / 16;
    float4 q0 = {0.f, 0.f, 0.f, 0.f}, q1 = {0.f, 0.f, 0.f, 0.f};
#pragma unroll 2
    for (int k2 = 0; k2 < 128; k2 += 4) {
        float4 x0 = *reinterpret_cast<const float4*>(&Xbuf[tr3 * 130 + k2]);
        float4 x1 = *reinterpret_cast<const float4*>(&Xbuf[(tr3 + 16) * 130 + k2]);
        float4 wv[4];
#pragma unroll
        for (int j = 0; j < 4; ++j)
            wv[j] = *reinterpret_cast<const float4*>(&Wbuf[(k2 + j) * 64 + tc3 * 4]);
        const float* p0 = reinterpret_cast<const float*>(&x0);
        const float* p1 = reinterpret_cast<const float*>(&x1);
#pragma unroll
        for (int j = 0; j < 4; ++j) {
            float s0 = p0[j], s1 = p1[j];
            q0.x += s0 * wv[j].x; q0.y += s0 * wv[j].y;
            q0.z += s0 * wv[j].z; q0.w += s0 * wv[j].w;
            q1.x += s1 * wv[j].x; q1.y += s1 * wv[j].y;
            q1.z += s1 * wv[j].z; q1.w += s1 * wv[j].w;
        }
    }
    int gr0 = r0 + tr3, gr1 = r0 + tr3 + 16;
    if (gr0 < n) {
        float dv = dinv[gr0];
        uint2 pk;
        pk.x = pack2(q0.x * dv, q0.y * dv);
        pk.y = pack2(q0.z * dv, q0.w * dv);
        *reinterpret_cast<uint2*>(&out[(size_t)gr0 * 64 + tc3 * 4]) = pk;
    }
    if (gr1 < n) {
        float dv = dinv[gr1];
        uint2 pk;
        pk.x = pack2(q1.x * dv, q1.y * dv);
        pk.y = pack2(q1.z * dv, q1.w * dv);
        *reinterpret_cast<uint2*>(&out[(size_t)gr1 * 64 + tc3 * 4]) = pk;
    }
}

// ---------------- pool + MLP + LayerNorm (one block / graph, 128 thr) --------

__global__ __launch_bounds__(128)
void poolmlp_kernel(const float* __restrict__ h, const int* __restrict__ goff,
                    const float* __restrict__ Wf1, const float* __restrict__ bf1,
                    const float* __restrict__ Wf2, const float* __restrict__ bf2,
                    const float* __restrict__ gamma, const float* __restrict__ beta,
                    float* __restrict__ out) {
    __shared__ float red[128];
    __shared__ float gs[64];
    __shared__ float ts[128];
    int g = blockIdx.x, t = threadIdx.x;
    int f = t & 63, half = t >> 6;
    int s = goff[g], e = goff[g + 1];
    float acc = 0.f;
    for (int i = s + half; i < e; i += 2) acc += h[(size_t)i * 64 + f];
    red[t] = acc;
    __syncthreads();
    if (t < 64) {
        float c = (float)(e - s);
        gs[t] = (red[t] + red[t + 64]) / fmaxf(c, 1.0f);
    }
    __syncthreads();
    float a1 = bf1[t];
    for (int k = 0; k < 64; ++k) a1 += gs[k] * Wf1[k * 128 + t];
    ts[t] = fmaxf(a1, 0.f);
    __syncthreads();
    if (t < 64) {
        float a2 = bf2[t];
        for (int k = 0; k < 128; ++k) a2 += ts[k] * Wf2[k * 64 + t];
        float u = fmaxf(a2, 0.f);
        float mu = u;
        for (int o = 1; o < 64; o <<= 1) mu += __shfl_xor(mu, o);
        mu *= (1.0f / 64.0f);
        float d = u - mu;
        float var = d * d;
        for (int o = 1; o < 64; o <<= 1) var += __shfl_xor(var, o);
        var *= (1.0f / 64.0f);
        out[g * 64 + t] = d * rsqrtf(var + 1e-5f) * gamma[t] + beta[t];
    }
}

// ---------------- launch ----------------

extern "C" void kernel_launch(void* const* d_in, const int* in_sizes, int n_in,
                              void* d_out, int out_size, void* d_ws, size_t ws_size,
                              hipStream_t stream) {
    const float* x     = (const float*)d_in[0];
    const int*   eidx  = (const int*)d_in[1];
    const int*   batch = (const int*)d_in[2];
    const float* W1 = (const float*)d_in[3];  const float* b1 = (const float*)d_in[4];
    const float* W2 = (const float*)d_in[5];  const float* b2 = (const float*)d_in[6];
    const float* W3 = (const float*)d_in[7];  const float* b3 = (const float*)d_in[8];
    const float* Wf1 = (const float*)d_in[9];  const float* bf1 = (const float*)d_in[10];
    const float* Wf2 = (const float*)d_in[11]; const float* bf2 = (const float*)d_in[12];
    const float* gamma = (const float*)d_in[13]; const float* beta = (const float*)d_in[14];
    float* out = (float*)d_out;

    const int n  = in_sizes[2];          // 50000
    const int E  = in_sizes[1] / 2;      // 600000
    const int ng = out_size / 64;        // 1000
    const int NB = (n + 1023) / 1024;    // 49

    const int* rows = eidx;              // edge_index[0] (sources)
    const int* cols = eidx + E;          // edge_index[1] (targets)

    // -------- workspace carve (zeroed region first, single memset) --------
    size_t off = 0;
    auto carve = [&](size_t bytes) {
        void* p = (char*)d_ws + off;
        off += (bytes + 511) & ~(size_t)511;
        return p;
    };
    int*   counts = (int*)  carve((size_t)n * 4);        // | zeroed
    int*   cursor = (int*)  carve((size_t)n * 4);        // | zeroed
    int*   gcnt   = (int*)  carve((size_t)(ng + 1) * 4); // | zeroed
    size_t zbytes = off;
    int*   offs   = (int*)  carve((size_t)(n + 1) * 4);
    int*   bsum   = (int*)  carve((size_t)(NB + 1) * 4);
    float* dinv   = (float*)carve((size_t)n * 4);
    int*   esrc   = (int*)  carve((size_t)E * 4);
    int*   goff   = (int*)  carve((size_t)(ng + 1) * 4);
    float*          t0  = (float*)         carve((size_t)n * 37 * 4);  // agg37 out
    unsigned short* h1b = (unsigned short*)carve((size_t)n * 64 * 2);  // mm1 out (bf16)
    float*          t1  = (float*)         carve((size_t)n * 64 * 4);  // agg64#1 out
    unsigned short* qb  = (unsigned short*)carve((size_t)n * 64 * 2);  // mm23 out (bf16)
    float*          h3  = (float*)         carve((size_t)n * 64 * 4);  // agg64#2 out
    (void)ws_size;

    hipMemsetAsync(d_ws, 0, zbytes, stream);

    // -------- CSR build + graph ranges + dinv --------
    int gH = (E + n + 255) / 256;
    hist_kernel<<<gH, 256, 0, stream>>>(cols, counts, E, batch, gcnt, n);
    scan1_kernel<<<NB, 1024, 0, stream>>>(counts, offs, bsum, n);
    scan_meta_kernel<<<1, 1024, 0, stream>>>(bsum, NB, gcnt, goff, ng, n);
    scan3_kernel<<<(n + 255) / 256, 256, 0, stream>>>(offs, bsum, counts, dinv, n, E);
    fill_kernel<<<(E + 255) / 256, 256, 0, stream>>>(rows, cols, offs, cursor, esrc, E);

    // -------- layers --------
    int gagg = (n + 3) / 4;
    // L1: t0 = dinv.*S(dinv.*x)   [fp32 gather of x]
    agg_kernel<37, 1, float><<<gagg, 256, 0, stream>>>(x, offs, esrc, dinv,
                                                       nullptr, 0, t0, n);
    //     h1' = relu(t0@W1+b1).*dinv  -> bf16
    mm1_kernel<<<(n + 31) / 32, 256, 0, stream>>>(t0, W1, b1, dinv, h1b, n);
    // L2: t1 = dinv.*S(h1')   [bf16 gather]
    agg_kernel<64, 0, unsigned short><<<gagg, 256, 0, stream>>>(h1b, offs, esrc, dinv,
                                                                nullptr, 0, t1, n);
    //     q = (relu(t1@W2+b2))@W3 .* dinv  -> bf16
    mm23_kernel<<<(n + 31) / 32, 256, 0, stream>>>(t1, W2, b2, W3, dinv, qb, n);
    // L3: h3 = relu(dinv.*S(q)+b3)   [bf16 gather]
    agg_kernel<64, 0, unsigned short><<<gagg, 256, 0, stream>>>(qb, offs, esrc, dinv,
                                                                b3, 1, h3, n);

    // -------- pool + MLP + LayerNorm --------
    poolmlp_kernel<<<ng, 128, 0, stream>>>(h3, goff, Wf1, bf1, Wf2, bf2, gamma, beta, out);
}